// Round 3
// baseline (488.327 us; speedup 1.0000x reference)
//
#include <hip/hip_runtime.h>
#include <math.h>

#define BATCH 8
#define NN    2048
#define FIN   128
#define FH    256
#define KP1   1639   // ceil(0.8*2048)
#define KP2   820    // ceil(0.5*1639)
#define CAP   64

// ---------------- norms of p1,p2 (fp64) -----------------------------------
__global__ __launch_bounds__(FH) void norms_kernel(const float* __restrict__ p1,
                                                   const float* __restrict__ p2,
                                                   double* __restrict__ norms) {
  __shared__ double red[FH];
  int t = threadIdx.x;
  double v = (double)p1[t];
  red[t] = v * v;
  __syncthreads();
  for (int s = FH / 2; s > 0; s >>= 1) { if (t < s) red[t] += red[t + s]; __syncthreads(); }
  if (t == 0) norms[0] = sqrt(red[0]);
  __syncthreads();
  v = (double)p2[t];
  red[t] = v * v;
  __syncthreads();
  for (int s = FH / 2; s > 0; s >>= 1) { if (t < s) red[t] += red[t + s]; __syncthreads(); }
  if (t == 0) norms[1] = sqrt(red[0]);
}

// ---------------- build CSC of A (one coalesced pass, float4) -------------
__global__ void build_csc1(const float* __restrict__ A, int* __restrict__ cnt,
                           int* __restrict__ idx, float* __restrict__ val) {
  const int total = BATCH * NN * (NN / 4);
  for (int t = blockIdx.x * blockDim.x + threadIdx.x; t < total;
       t += gridDim.x * blockDim.x) {
    float4 v4 = reinterpret_cast<const float4*>(A)[t];
    int b = t / (NN * NN / 4);
    int rem = t % (NN * NN / 4);
    int j = rem / (NN / 4);
    int i0 = (rem % (NN / 4)) * 4;
    float vv[4] = {v4.x, v4.y, v4.z, v4.w};
#pragma unroll
    for (int c = 0; c < 4; ++c) {
      float v = vv[c];
      if (v != 0.0f) {
        int col = b * NN + i0 + c;
        int p = atomicAdd(&cnt[col], 1);
        if (p < CAP) { idx[col * CAP + p] = j; val[col * CAP + p] = v; }
      }
    }
  }
}

// -------- canonicalize columns (sort by j); dinv in fp64 ------------------
__global__ void canon_cols(int* __restrict__ cnt, int* __restrict__ idx,
                           float* __restrict__ val, double* __restrict__ dinv) {
  int col = blockIdx.x * blockDim.x + threadIdx.x;
  if (col >= BATCH * NN) return;
  int c = cnt[col]; if (c > CAP) c = CAP; cnt[col] = c;
  int* ji = idx + (size_t)col * CAP;
  float* jv = val + (size_t)col * CAP;
  for (int a = 1; a < c; ++a) {
    int kj = ji[a]; float kv = jv[a];
    int q = a - 1;
    while (q >= 0 && ji[q] > kj) { ji[q + 1] = ji[q]; jv[q + 1] = jv[q]; --q; }
    ji[q + 1] = kj; jv[q + 1] = kv;
  }
  double s = 1.0;
  for (int a = 0; a < c; ++a) s += (double)jv[a];
  dinv[col] = 1.0 / sqrt(s);
}

// ------- Y = dinv[row] * (X @ W)  in fp64  (16 rows x 256 cols/block) -----
template <int KD, typename TX>
__global__ __launch_bounds__(256) void gemm_y(const TX* __restrict__ X,
                                              const float* __restrict__ W,
                                              const double* __restrict__ dinv,
                                              double* __restrict__ Y, int rows) {
  int b = blockIdx.y;
  int r0 = blockIdx.x * 16;
  int f = threadIdx.x;
  __shared__ double xs[16][KD];
  const TX* Xb = X + (size_t)b * NN * KD;
  for (int e = threadIdx.x; e < 16 * KD; e += 256) {
    int r = e / KD, k = e % KD;
    xs[r][k] = (r0 + r < rows) ? (double)Xb[(size_t)(r0 + r) * KD + k] : 0.0;
  }
  __syncthreads();
  double acc[16];
#pragma unroll
  for (int r = 0; r < 16; ++r) acc[r] = 0.0;
  for (int k = 0; k < KD; k += 2) {
    double w0 = (double)W[(k + 0) * FH + f];
    double w1 = (double)W[(k + 1) * FH + f];
#pragma unroll
    for (int r = 0; r < 16; ++r) {
      acc[r] += xs[r][k] * w0 + xs[r][k + 1] * w1;
    }
  }
#pragma unroll
  for (int r = 0; r < 16; ++r) {
    int row = r0 + r;
    if (row < rows) Y[((size_t)b * NN + row) * FH + f] = dinv[b * NN + row] * acc[r];
  }
}

// ---- h = relu(dinv*(self + sum nz) + bias) fp64; dot = h . p fp64 --------
__global__ __launch_bounds__(FH) void aggregate(
    const double* __restrict__ Y, const int* __restrict__ cnt,
    const int* __restrict__ idx, const float* __restrict__ val,
    const double* __restrict__ dinv, const float* __restrict__ bias,
    const float* __restrict__ p, double* __restrict__ H, double* __restrict__ dot) {
  int b = blockIdx.y, i = blockIdx.x, f = threadIdx.x;
  int col = b * NN + i;
  const int* ji = idx + (size_t)col * CAP;
  const float* jv = val + (size_t)col * CAP;
  double acc = Y[(size_t)col * FH + f];  // self loop: dinv_i * xW_i
  int c = cnt[col];
  for (int a = 0; a < c; ++a) {
    int j = ji[a];
    double v = (double)jv[a];
    acc += v * Y[((size_t)b * NN + j) * FH + f];
  }
  double h = fmax(dinv[col] * acc + (double)bias[f], 0.0);
  H[(size_t)col * FH + f] = h;
  __shared__ double red[FH];
  red[f] = h * (double)p[f];
  __syncthreads();
  for (int s = FH / 2; s > 0; s >>= 1) { if (f < s) red[f] += red[f + s]; __syncthreads(); }
  if (f == 0) dot[col] = red[0];
}

// ---- full bitonic sort, fp64 keys (score desc, idx asc on exact ties) ----
__global__ __launch_bounds__(1024) void topk_sort(
    const double* __restrict__ dot, const double* __restrict__ norms, int which,
    int valid, int k, int* __restrict__ perm, double* __restrict__ vals) {
  __shared__ double sk[NN];
  __shared__ int si[NN];
  int b = blockIdx.x, t = threadIdx.x;
  double nrm = norms[which];
  for (int e = t; e < NN; e += 1024) {
    sk[e] = (e < valid) ? tanh(dot[b * NN + e] / nrm) : -1.0e300;
    si[e] = e;
  }
  for (int kk = 2; kk <= NN; kk <<= 1) {
    for (int j = kk >> 1; j > 0; j >>= 1) {
      __syncthreads();
      int i = ((t & ~(j - 1)) << 1) | (t & (j - 1));
      int q = i | j;
      double ka = sk[i], kb = sk[q];
      int ia = si[i], ib = si[q];
      bool p_first = (kb > ka) || (kb == ka && ib < ia);  // q-elem sorts before i-elem
      bool up = ((i & kk) == 0);
      if (up ? p_first : !p_first) { sk[i] = kb; sk[q] = ka; si[i] = ib; si[q] = ia; }
    }
  }
  __syncthreads();
  for (int e = t; e < k; e += 1024) {
    perm[b * NN + e] = si[e];
    vals[b * NN + e] = sk[e];
  }
}

// -------- pool1: gather h[perm]*val (fp64), build inverse rank map --------
__global__ __launch_bounds__(FH) void pool1_kernel(
    const double* __restrict__ H, const int* __restrict__ perm,
    const double* __restrict__ vals, double* __restrict__ HP, int* __restrict__ inv) {
  int b = blockIdx.y, r = blockIdx.x, f = threadIdx.x;
  int node = perm[b * NN + r];
  double s = vals[b * NN + r];
  if (f == 0) inv[b * NN + node] = r;
  HP[((size_t)b * NN + r) * FH + f] = H[((size_t)b * NN + node) * FH + f] * s;
}

// -------- CSC of A1 = A[perm][:,perm] from CSC1 + inv map -----------------
__global__ void build_csc2(const int* __restrict__ cnt1, const int* __restrict__ idx1,
                           const float* __restrict__ val1, const int* __restrict__ perm,
                           const int* __restrict__ inv, int* __restrict__ cnt2,
                           int* __restrict__ idx2, float* __restrict__ val2,
                           double* __restrict__ dinv2) {
  int b = blockIdx.y;
  int ri = blockIdx.x * blockDim.x + threadIdx.x;
  if (ri >= KP1) return;
  int i = perm[b * NN + ri];
  int colA = b * NN + i;
  int c = cnt1[colA];
  const int* ji = idx1 + (size_t)colA * CAP;
  const float* jv = val1 + (size_t)colA * CAP;
  int colB = b * NN + ri;
  int* oj = idx2 + (size_t)colB * CAP;
  float* ov = val2 + (size_t)colB * CAP;
  int m = 0;
  double s = 1.0;
  for (int a = 0; a < c; ++a) {
    int rj = inv[b * NN + ji[a]];
    if (rj >= 0) { oj[m] = rj; ov[m] = jv[a]; s += (double)jv[a]; ++m; }
  }
  cnt2[colB] = m;
  dinv2[colB] = 1.0 / sqrt(s);
}

// -------- final scatter: rows [0,KP2) = h2[perm2]*vals2, rest zeros -------
__global__ __launch_bounds__(FH) void final_kernel(
    const double* __restrict__ H2, const int* __restrict__ perm2,
    const double* __restrict__ vals2, float* __restrict__ out) {
  int b = blockIdx.y, r = blockIdx.x, f = threadIdx.x;
  float o = 0.0f;
  if (r < KP2) {
    int rr = perm2[b * NN + r];
    o = (float)(H2[((size_t)b * NN + rr) * FH + f] * vals2[b * NN + r]);
  }
  out[((size_t)b * NN + r) * FH + f] = o;
}

extern "C" void kernel_launch(void* const* d_in, const int* in_sizes, int n_in,
                              void* d_out, int out_size, void* d_ws, size_t ws_size,
                              hipStream_t stream) {
  const float* x  = (const float*)d_in[0];
  const float* A  = (const float*)d_in[1];
  const float* W1 = (const float*)d_in[2];
  const float* b1 = (const float*)d_in[3];
  const float* p1 = (const float*)d_in[4];
  const float* W2 = (const float*)d_in[5];
  const float* b2 = (const float*)d_in[6];
  const float* p2 = (const float*)d_in[7];
  float* out = (float*)d_out;

  char* ws = (char*)d_ws;
  size_t off = 0;
  auto alloc = [&](size_t bytes) {
    void* p = ws + off;
    off += (bytes + 255) & ~(size_t)255;
    return p;
  };
  double* dot   = (double*)alloc((size_t)BATCH * NN * 8);
  double* y     = (double*)alloc((size_t)BATCH * NN * FH * 8);
  double* h     = (double*)alloc((size_t)BATCH * NN * FH * 8);
  double* hp    = (double*)alloc((size_t)BATCH * NN * FH * 8);
  double* dinv1 = (double*)alloc((size_t)BATCH * NN * 8);
  double* dinv2 = (double*)alloc((size_t)BATCH * NN * 8);
  int*   cnt1  = (int*)alloc((size_t)BATCH * NN * 4);
  int*   idx1  = (int*)alloc((size_t)BATCH * NN * CAP * 4);
  float* val1  = (float*)alloc((size_t)BATCH * NN * CAP * 4);
  int*   cnt2  = (int*)alloc((size_t)BATCH * NN * 4);
  int*   idx2  = (int*)alloc((size_t)BATCH * NN * CAP * 4);
  float* val2  = (float*)alloc((size_t)BATCH * NN * CAP * 4);
  int*   perm1 = (int*)alloc((size_t)BATCH * NN * 4);
  double* vals1 = (double*)alloc((size_t)BATCH * NN * 8);
  int*   perm2 = (int*)alloc((size_t)BATCH * NN * 4);
  double* vals2 = (double*)alloc((size_t)BATCH * NN * 8);
  int*   inv   = (int*)alloc((size_t)BATCH * NN * 4);
  double* norms = (double*)alloc(64);

  hipMemsetAsync(cnt1, 0, (size_t)BATCH * NN * 4, stream);
  hipMemsetAsync(inv, 0xFF, (size_t)BATCH * NN * 4, stream);

  norms_kernel<<<1, FH, 0, stream>>>(p1, p2, norms);
  build_csc1<<<4096, 256, 0, stream>>>(A, cnt1, idx1, val1);
  canon_cols<<<(BATCH * NN + 255) / 256, 256, 0, stream>>>(cnt1, idx1, val1, dinv1);
  gemm_y<FIN, float><<<dim3(NN / 16, BATCH), 256, 0, stream>>>(x, W1, dinv1, y, NN);
  aggregate<<<dim3(NN, BATCH), FH, 0, stream>>>(y, cnt1, idx1, val1, dinv1, b1, p1, h, dot);
  topk_sort<<<BATCH, 1024, 0, stream>>>(dot, norms, 0, NN, KP1, perm1, vals1);
  pool1_kernel<<<dim3(KP1, BATCH), FH, 0, stream>>>(h, perm1, vals1, hp, inv);
  build_csc2<<<dim3((KP1 + 255) / 256, BATCH), 256, 0, stream>>>(cnt1, idx1, val1, perm1,
                                                                inv, cnt2, idx2, val2, dinv2);
  gemm_y<FH, double><<<dim3((KP1 + 15) / 16, BATCH), 256, 0, stream>>>(hp, W2, dinv2, y, KP1);
  aggregate<<<dim3(KP1, BATCH), FH, 0, stream>>>(y, cnt2, idx2, val2, dinv2, b2, p2, h, dot);
  topk_sort<<<BATCH, 1024, 0, stream>>>(dot, norms, 1, KP1, KP2, perm2, vals2);
  final_kernel<<<dim3(NN, BATCH), FH, 0, stream>>>(h, perm2, vals2, out);
}

// Round 4
// 392.199 us; speedup vs baseline: 1.2451x; 1.2451x over previous
//
#include <hip/hip_runtime.h>
#include <math.h>

#define BATCH 8
#define NN    2048
#define FIN   128
#define FH    256
#define KP1   1639   // ceil(0.8*2048)
#define KP2   820    // ceil(0.5*1639)
#define CAP   64

// ---------------- norms of p1,p2 (fp64) -----------------------------------
__global__ __launch_bounds__(FH) void norms_kernel(const float* __restrict__ p1,
                                                   const float* __restrict__ p2,
                                                   double* __restrict__ norms) {
  __shared__ double red[FH];
  int t = threadIdx.x;
  double v = (double)p1[t];
  red[t] = v * v;
  __syncthreads();
  for (int s = FH / 2; s > 0; s >>= 1) { if (t < s) red[t] += red[t + s]; __syncthreads(); }
  if (t == 0) norms[0] = sqrt(red[0]);
  __syncthreads();
  v = (double)p2[t];
  red[t] = v * v;
  __syncthreads();
  for (int s = FH / 2; s > 0; s >>= 1) { if (t < s) red[t] += red[t + s]; __syncthreads(); }
  if (t == 0) norms[1] = sqrt(red[0]);
}

// ---------------- build CSC of A (one coalesced pass, float4) -------------
__global__ void build_csc1(const float* __restrict__ A, int* __restrict__ cnt,
                           int* __restrict__ idx, float* __restrict__ val) {
  const int total = BATCH * NN * (NN / 4);
  for (int t = blockIdx.x * blockDim.x + threadIdx.x; t < total;
       t += gridDim.x * blockDim.x) {
    float4 v4 = reinterpret_cast<const float4*>(A)[t];
    int b = t / (NN * NN / 4);
    int rem = t % (NN * NN / 4);
    int j = rem / (NN / 4);
    int i0 = (rem % (NN / 4)) * 4;
    float vv[4] = {v4.x, v4.y, v4.z, v4.w};
#pragma unroll
    for (int c = 0; c < 4; ++c) {
      float v = vv[c];
      if (v != 0.0f) {
        int col = b * NN + i0 + c;
        int p = atomicAdd(&cnt[col], 1);
        if (p < CAP) { idx[col * CAP + p] = j; val[col * CAP + p] = v; }
      }
    }
  }
}

// ------ canonicalize: one WAVE per column, in-register bitonic sort -------
__global__ __launch_bounds__(256) void canon_cols(int* __restrict__ cnt,
                                                  int* __restrict__ idx,
                                                  float* __restrict__ val,
                                                  double* __restrict__ dinv) {
  int wid = (blockIdx.x * blockDim.x + threadIdx.x) >> 6;
  int lane = threadIdx.x & 63;
  if (wid >= BATCH * NN) return;
  int c = cnt[wid]; if (c > CAP) c = CAP;
  if (lane == 0) cnt[wid] = c;
  int key = 0x7fffffff;
  float v = 0.0f;
  if (lane < c) {
    key = idx[(size_t)wid * CAP + lane];
    v = val[(size_t)wid * CAP + lane];
  }
  // 64-lane bitonic sort ascending by key
#pragma unroll
  for (int k = 2; k <= 64; k <<= 1) {
#pragma unroll
    for (int j = k >> 1; j > 0; j >>= 1) {
      int pk = __shfl_xor(key, j);
      float pv = __shfl_xor(v, j);
      bool up = ((lane & k) == 0);
      bool takeMin = (((lane & j) == 0) == up);
      bool sw = takeMin ? (pk < key) : (pk > key);
      if (sw) { key = pk; v = pv; }
    }
  }
  if (lane < c) {
    idx[(size_t)wid * CAP + lane] = key;
    val[(size_t)wid * CAP + lane] = v;
  }
  double dv = (double)v;
#pragma unroll
  for (int off = 32; off > 0; off >>= 1) dv += __shfl_xor(dv, off);
  if (lane == 0) dinv[wid] = 1.0 / sqrt(1.0 + dv);
}

// ------- Y = dinv[row] * (X @ W)  in fp64  (16 rows x 256 cols/block) -----
template <int KD, typename TX>
__global__ __launch_bounds__(256) void gemm_y(const TX* __restrict__ X,
                                              const float* __restrict__ W,
                                              const double* __restrict__ dinv,
                                              double* __restrict__ Y, int rows) {
  int b = blockIdx.y;
  int r0 = blockIdx.x * 16;
  int f = threadIdx.x;
  __shared__ double xs[16][KD];
  const TX* Xb = X + (size_t)b * NN * KD;
  for (int e = threadIdx.x; e < 16 * KD; e += 256) {
    int r = e / KD, k = e % KD;
    xs[r][k] = (r0 + r < rows) ? (double)Xb[(size_t)(r0 + r) * KD + k] : 0.0;
  }
  __syncthreads();
  double acc[16];
#pragma unroll
  for (int r = 0; r < 16; ++r) acc[r] = 0.0;
  for (int k = 0; k < KD; k += 2) {
    double w0 = (double)W[(k + 0) * FH + f];
    double w1 = (double)W[(k + 1) * FH + f];
#pragma unroll
    for (int r = 0; r < 16; ++r) {
      double2 xv = *reinterpret_cast<const double2*>(&xs[r][k]);  // ds_read_b128
      acc[r] += xv.x * w0 + xv.y * w1;
    }
  }
#pragma unroll
  for (int r = 0; r < 16; ++r) {
    int row = r0 + r;
    if (row < rows) Y[((size_t)b * NN + row) * FH + f] = dinv[b * NN + row] * acc[r];
  }
}

// ---- h = relu(dinv*(self + sum nz) + bias) fp64; dot = h . p fp64 --------
__global__ __launch_bounds__(FH) void aggregate(
    const double* __restrict__ Y, const int* __restrict__ cnt,
    const int* __restrict__ idx, const float* __restrict__ val,
    const double* __restrict__ dinv, const float* __restrict__ bias,
    const float* __restrict__ p, double* __restrict__ H, double* __restrict__ dot) {
  int b = blockIdx.y, i = blockIdx.x, f = threadIdx.x;
  int col = b * NN + i;
  const int* ji = idx + (size_t)col * CAP;
  const float* jv = val + (size_t)col * CAP;
  double acc = Y[(size_t)col * FH + f];  // self loop: dinv_i * xW_i
  int c = cnt[col];
  for (int a = 0; a < c; ++a) {
    int j = ji[a];
    double v = (double)jv[a];
    acc += v * Y[((size_t)b * NN + j) * FH + f];
  }
  double h = fmax(dinv[col] * acc + (double)bias[f], 0.0);
  H[(size_t)col * FH + f] = h;
  __shared__ double red[FH];
  red[f] = h * (double)p[f];
  __syncthreads();
  for (int s = FH / 2; s > 0; s >>= 1) { if (f < s) red[f] += red[f + s]; __syncthreads(); }
  if (f == 0) dot[col] = red[0];
}

// ---- full bitonic sort, fp64 keys (score desc, idx asc on exact ties) ----
__global__ __launch_bounds__(1024) void topk_sort(
    const double* __restrict__ dot, const double* __restrict__ norms, int which,
    int valid, int k, int* __restrict__ perm, double* __restrict__ vals) {
  __shared__ double sk[NN];
  __shared__ int si[NN];
  int b = blockIdx.x, t = threadIdx.x;
  double nrm = norms[which];
  for (int e = t; e < NN; e += 1024) {
    sk[e] = (e < valid) ? tanh(dot[b * NN + e] / nrm) : -1.0e300;
    si[e] = e;
  }
  for (int kk = 2; kk <= NN; kk <<= 1) {
    for (int j = kk >> 1; j > 0; j >>= 1) {
      __syncthreads();
      int i = ((t & ~(j - 1)) << 1) | (t & (j - 1));
      int q = i | j;
      double ka = sk[i], kb = sk[q];
      int ia = si[i], ib = si[q];
      bool p_first = (kb > ka) || (kb == ka && ib < ia);  // q-elem sorts before i-elem
      bool up = ((i & kk) == 0);
      if (up ? p_first : !p_first) { sk[i] = kb; sk[q] = ka; si[i] = ib; si[q] = ia; }
    }
  }
  __syncthreads();
  for (int e = t; e < k; e += 1024) {
    perm[b * NN + e] = si[e];
    vals[b * NN + e] = sk[e];
  }
}

// -------- pool1: gather h[perm]*val (fp64), build inverse rank map --------
__global__ __launch_bounds__(FH) void pool1_kernel(
    const double* __restrict__ H, const int* __restrict__ perm,
    const double* __restrict__ vals, double* __restrict__ HP, int* __restrict__ inv) {
  int b = blockIdx.y, r = blockIdx.x, f = threadIdx.x;
  int node = perm[b * NN + r];
  double s = vals[b * NN + r];
  if (f == 0) inv[b * NN + node] = r;
  HP[((size_t)b * NN + r) * FH + f] = H[((size_t)b * NN + node) * FH + f] * s;
}

// ------ CSC of A1 = A[perm][:,perm]: one WAVE per column, ballot-compact --
__global__ __launch_bounds__(256) void build_csc2(
    const int* __restrict__ cnt1, const int* __restrict__ idx1,
    const float* __restrict__ val1, const int* __restrict__ perm,
    const int* __restrict__ inv, int* __restrict__ cnt2, int* __restrict__ idx2,
    float* __restrict__ val2, double* __restrict__ dinv2) {
  int wid = (blockIdx.x * blockDim.x + threadIdx.x) >> 6;
  int lane = threadIdx.x & 63;
  if (wid >= BATCH * KP1) return;
  int b = wid / KP1, ri = wid % KP1;
  int colA = b * NN + perm[b * NN + ri];
  int c = cnt1[colA];
  int rj = -1;
  float v = 0.0f;
  if (lane < c) {
    int j = idx1[(size_t)colA * CAP + lane];
    v = val1[(size_t)colA * CAP + lane];
    rj = inv[b * NN + j];
  }
  bool keep = (lane < c) && (rj >= 0);
  unsigned long long mask = __ballot(keep);
  int pos = __popcll(mask & ((1ull << lane) - 1ull));
  int colB = b * NN + ri;
  if (keep) {
    idx2[(size_t)colB * CAP + pos] = rj;
    val2[(size_t)colB * CAP + pos] = v;
  }
  if (lane == 0) cnt2[colB] = (int)__popcll(mask);
  double dv = keep ? (double)v : 0.0;
#pragma unroll
  for (int off = 32; off > 0; off >>= 1) dv += __shfl_xor(dv, off);
  if (lane == 0) dinv2[colB] = 1.0 / sqrt(1.0 + dv);
}

// -------- final scatter: rows [0,KP2) = h2[perm2]*vals2, rest zeros -------
__global__ __launch_bounds__(FH) void final_kernel(
    const double* __restrict__ H2, const int* __restrict__ perm2,
    const double* __restrict__ vals2, float* __restrict__ out) {
  int b = blockIdx.y, r = blockIdx.x, f = threadIdx.x;
  float o = 0.0f;
  if (r < KP2) {
    int rr = perm2[b * NN + r];
    o = (float)(H2[((size_t)b * NN + rr) * FH + f] * vals2[b * NN + r]);
  }
  out[((size_t)b * NN + r) * FH + f] = o;
}

extern "C" void kernel_launch(void* const* d_in, const int* in_sizes, int n_in,
                              void* d_out, int out_size, void* d_ws, size_t ws_size,
                              hipStream_t stream) {
  const float* x  = (const float*)d_in[0];
  const float* A  = (const float*)d_in[1];
  const float* W1 = (const float*)d_in[2];
  const float* b1 = (const float*)d_in[3];
  const float* p1 = (const float*)d_in[4];
  const float* W2 = (const float*)d_in[5];
  const float* b2 = (const float*)d_in[6];
  const float* p2 = (const float*)d_in[7];
  float* out = (float*)d_out;

  char* ws = (char*)d_ws;
  size_t off = 0;
  auto alloc = [&](size_t bytes) {
    void* p = ws + off;
    off += (bytes + 255) & ~(size_t)255;
    return p;
  };
  double* dot   = (double*)alloc((size_t)BATCH * NN * 8);
  double* y     = (double*)alloc((size_t)BATCH * NN * FH * 8);
  double* h     = (double*)alloc((size_t)BATCH * NN * FH * 8);
  double* hp    = (double*)alloc((size_t)BATCH * NN * FH * 8);
  double* dinv1 = (double*)alloc((size_t)BATCH * NN * 8);
  double* dinv2 = (double*)alloc((size_t)BATCH * NN * 8);
  int*   cnt1  = (int*)alloc((size_t)BATCH * NN * 4);
  int*   idx1  = (int*)alloc((size_t)BATCH * NN * CAP * 4);
  float* val1  = (float*)alloc((size_t)BATCH * NN * CAP * 4);
  int*   cnt2  = (int*)alloc((size_t)BATCH * NN * 4);
  int*   idx2  = (int*)alloc((size_t)BATCH * NN * CAP * 4);
  float* val2  = (float*)alloc((size_t)BATCH * NN * CAP * 4);
  int*   perm1 = (int*)alloc((size_t)BATCH * NN * 4);
  double* vals1 = (double*)alloc((size_t)BATCH * NN * 8);
  int*   perm2 = (int*)alloc((size_t)BATCH * NN * 4);
  double* vals2 = (double*)alloc((size_t)BATCH * NN * 8);
  int*   inv   = (int*)alloc((size_t)BATCH * NN * 4);
  double* norms = (double*)alloc(64);

  hipMemsetAsync(cnt1, 0, (size_t)BATCH * NN * 4, stream);
  hipMemsetAsync(inv, 0xFF, (size_t)BATCH * NN * 4, stream);

  norms_kernel<<<1, FH, 0, stream>>>(p1, p2, norms);
  build_csc1<<<4096, 256, 0, stream>>>(A, cnt1, idx1, val1);
  canon_cols<<<(BATCH * NN * 64) / 256, 256, 0, stream>>>(cnt1, idx1, val1, dinv1);
  gemm_y<FIN, float><<<dim3(NN / 16, BATCH), 256, 0, stream>>>(x, W1, dinv1, y, NN);
  aggregate<<<dim3(NN, BATCH), FH, 0, stream>>>(y, cnt1, idx1, val1, dinv1, b1, p1, h, dot);
  topk_sort<<<BATCH, 1024, 0, stream>>>(dot, norms, 0, NN, KP1, perm1, vals1);
  pool1_kernel<<<dim3(KP1, BATCH), FH, 0, stream>>>(h, perm1, vals1, hp, inv);
  build_csc2<<<(BATCH * KP1 * 64 + 255) / 256, 256, 0, stream>>>(cnt1, idx1, val1, perm1,
                                                                 inv, cnt2, idx2, val2, dinv2);
  gemm_y<FH, double><<<dim3((KP1 + 15) / 16, BATCH), 256, 0, stream>>>(hp, W2, dinv2, y, KP1);
  aggregate<<<dim3(KP1, BATCH), FH, 0, stream>>>(y, cnt2, idx2, val2, dinv2, b2, p2, h, dot);
  topk_sort<<<BATCH, 1024, 0, stream>>>(dot, norms, 1, KP1, KP2, perm2, vals2);
  final_kernel<<<dim3(NN, BATCH), FH, 0, stream>>>(h, perm2, vals2, out);
}